// Round 2
// baseline (1152.306 us; speedup 1.0000x reference)
//
#include <hip/hip_runtime.h>
#include <cstdint>
#include <cstddef>

#define TPB 256

static constexpr int kHW  = 4096;
static constexpr int kWid = 64;
static constexpr int kC   = 256;
static constexpr int kCQK = 64;

// ---- workspace layout (float offsets) ----
static constexpr size_t OFF_WQT = 0;                      // [9][256][64]   (tap, ci, co)
static constexpr size_t OFF_WKT = OFF_WQT + 147456;       // [9][256][64]
static constexpr size_t OFF_WVT = OFF_WKT + 147456;       // [256 ci][256 co]
static constexpr size_t OFF_WOT = OFF_WVT + 65536;        // [256 ci][256 co]
static constexpr size_t OFF_QP  = OFF_WOT + 65536;        // [4][64][4096] conv-q partials
static constexpr size_t OFF_KP  = OFF_QP  + 1048576;      // [4][64][4096] conv-k partials
static constexpr size_t OFF_VV  = OFF_KP  + 1048576;      // [256][4096]   v (conv1x1 out)
static constexpr size_t OFF_RR  = OFF_VV  + 1048576;      // [4096][256]   attn@v, px-major
static constexpr size_t OFF_TMP = OFF_RR  + 1048576;      // [256][4096]   conv-o out
static constexpr size_t OFF_QS  = OFF_TMP + 1048576;      // [64][4096]    q summed+scaled
static constexpr size_t OFF_KS  = OFF_QS  + 262144;       // [64][4096]    k summed
// total = 6,193,152 floats ~= 24.8 MB

// ---------------------------------------------------------------- prep: transpose weights
__global__ void k_prep(const float* __restrict__ wq, const float* __restrict__ wk,
                       const float* __restrict__ wv, const float* __restrict__ wo,
                       float* __restrict__ wsf) {
  int id = blockIdx.x * TPB + threadIdx.x;
  if (id < 147456) {
    int co = id & 63, ci = (id >> 6) & 255, tap = id >> 14;
    wsf[OFF_WQT + id] = wq[(co * 256 + ci) * 9 + tap];
    wsf[OFF_WKT + id] = wk[(co * 256 + ci) * 9 + tap];
  }
  if (id < 65536) {
    int co = id & 255, ci = id >> 8;
    wsf[OFF_WVT + id] = wv[co * 256 + ci];
    wsf[OFF_WOT + id] = wo[co * 256 + ci];
  }
}

// ---------------------------------------------------------------- 3x3 conv (q & k), ci-split x4
// block: 256 thr = 4 waves; lane = x (full image row), wave = 16-co group. Weights via s_load.
__global__ __launch_bounds__(TPB) void k_conv3(const float* __restrict__ q_in,
                                               const float* __restrict__ k_in,
                                               const float* __restrict__ qpe,
                                               const float* __restrict__ kpe,
                                               float* __restrict__ wsf) {
  const int which = blockIdx.z;           // 0:q 1:k
  const int ks    = blockIdx.y;           // ci split 0..3
  const int y     = blockIdx.x;           // image row
  const int lane  = threadIdx.x & 63;
  const int wave  = threadIdx.x >> 6;
  const int co0   = __builtin_amdgcn_readfirstlane(wave << 4);
  const float* in0 = which ? k_in : q_in;
  const float* pos = which ? kpe : qpe;
  const float* wt  = wsf + (which ? OFF_WKT : OFF_WQT);
  float* outp = wsf + (which ? OFF_KP : OFF_QP) + (size_t)ks * (kCQK * kHW);

  float acc[16];
#pragma unroll
  for (int j = 0; j < 16; ++j) acc[j] = 0.f;

  const int x = lane;
  const int ci0 = ks * 64;
  for (int ci = ci0; ci < ci0 + 64; ++ci) {
    int base = ci * kHW + y * kWid + x;
    float c0 = (y > 0)  ? (in0[base - 64] + pos[base - 64]) : 0.f;
    float c1 = in0[base] + pos[base];
    float c2 = (y < 63) ? (in0[base + 64] + pos[base + 64]) : 0.f;
    // x-1 / x+1 taps via intra-wave shuffle; row boundary -> zero pad
    float l0 = __shfl(c0, (lane + 63) & 63, 64); l0 = (lane == 0) ? 0.f : l0;
    float l1 = __shfl(c1, (lane + 63) & 63, 64); l1 = (lane == 0) ? 0.f : l1;
    float l2 = __shfl(c2, (lane + 63) & 63, 64); l2 = (lane == 0) ? 0.f : l2;
    float r0 = __shfl(c0, (lane + 1) & 63, 64);  r0 = (lane == 63) ? 0.f : r0;
    float r1 = __shfl(c1, (lane + 1) & 63, 64);  r1 = (lane == 63) ? 0.f : r1;
    float r2 = __shfl(c2, (lane + 1) & 63, 64);  r2 = (lane == 63) ? 0.f : r2;
    float iv[9] = {l0, c0, r0, l1, c1, r1, l2, c2, r2};
#pragma unroll
    for (int tap = 0; tap < 9; ++tap) {
      const float* wrow = wt + ((size_t)tap * 256 + ci) * 64 + co0;  // uniform -> s_load
#pragma unroll
      for (int j = 0; j < 16; ++j) acc[j] = fmaf(wrow[j], iv[tap], acc[j]);
    }
  }
#pragma unroll
  for (int j = 0; j < 16; ++j) outp[(size_t)(co0 + j) * kHW + y * kWid + x] = acc[j];
}

// ---------------------------------------------------------------- sum ci-split partials (+bias, q scaled)
__global__ void k_sumqk(const float* __restrict__ bq, const float* __restrict__ bk,
                        float* __restrict__ wsf) {
  int i = blockIdx.x * TPB + threadIdx.x;
  if (i >= kCQK * kHW) return;
  int c = i >> 12;
  float q = wsf[OFF_QP + i] + wsf[OFF_QP + 262144 + i] + wsf[OFF_QP + 524288 + i] +
            wsf[OFF_QP + 786432 + i] + bq[c];
  wsf[OFF_QS + i] = q * 0.35355339059327379f;  // D^-0.5
  wsf[OFF_KS + i] = wsf[OFF_KP + i] + wsf[OFF_KP + 262144 + i] + wsf[OFF_KP + 524288 + i] +
                    wsf[OFF_KP + 786432 + i] + bk[c];
}

// ---------------------------------------------------------------- 1x1 conv for v (+bv folded)
__global__ __launch_bounds__(TPB) void k_convv(const float* __restrict__ value,
                                               const float* __restrict__ bv,
                                               float* __restrict__ wsf) {
  const float* wvt = wsf + OFF_WVT;
  float* vout = wsf + OFF_VV;
  int y = blockIdx.x, cb = blockIdx.y;
  int lane = threadIdx.x & 63, wave = threadIdx.x >> 6;
  int co0 = __builtin_amdgcn_readfirstlane(cb * 64 + (wave << 4));
  int px = y * kWid + lane;
  float acc[16];
#pragma unroll
  for (int j = 0; j < 16; ++j) acc[j] = bv[co0 + j];   // uniform s_load
  for (int ci = 0; ci < 256; ++ci) {
    float xv = value[ci * kHW + px];
    const float* wrow = wvt + ci * 256 + co0;  // uniform -> s_load
#pragma unroll
    for (int j = 0; j < 16; ++j) acc[j] = fmaf(wrow[j], xv, acc[j]);
  }
#pragma unroll
  for (int j = 0; j < 16; ++j) vout[(size_t)(co0 + j) * kHW + px] = acc[j];
}

// ---------------------------------------------------------------- fused attention
// grid (256 qb, 8 h); block 256 thr = 4 waves x 4 rows. Two passes over K:
// pass1: l = sum exp(e); pass2: recompute e, write attn=exp(e)/l, accumulate PV in regs.
__global__ __launch_bounds__(TPB) void k_attn(const float* __restrict__ wsf,
                                              float* __restrict__ rr,
                                              float* __restrict__ attn_out) {
  __shared__ float k_s[8][260];
  __shared__ float v_s[256][36];
  const int h = blockIdx.y;
  const int qb = blockIdx.x;
  const int tid = threadIdx.x;
  const int lane = tid & 63;
  const int wave = tid >> 6;
  const int qi0 = __builtin_amdgcn_readfirstlane(qb * 16 + wave * 4);

  const float* qs = wsf + OFF_QS;
  const float* ks = wsf + OFF_KS;
  const float* vv = wsf + OFF_VV;

  float qreg[4][8];
#pragma unroll
  for (int r = 0; r < 4; ++r)
#pragma unroll
    for (int d = 0; d < 8; ++d) qreg[r][d] = qs[(h * 8 + d) * kHW + qi0 + r];

  float l[4] = {0.f, 0.f, 0.f, 0.f};
  // ---- pass 1: denominators ----
  for (int s = 0; s < 16; ++s) {
    int k0 = s * 256;
    __syncthreads();
    for (int idx = tid; idx < 8 * 256; idx += TPB) {
      int d = idx >> 8, kk = idx & 255;
      k_s[d][kk] = ks[(h * 8 + d) * kHW + k0 + kk];
    }
    __syncthreads();
#pragma unroll
    for (int sub = 0; sub < 4; ++sub) {
      int kl = sub * 64 + lane;
      float kv[8];
#pragma unroll
      for (int d = 0; d < 8; ++d) kv[d] = k_s[d][kl];
#pragma unroll
      for (int r = 0; r < 4; ++r) {
        float e = 0.f;
#pragma unroll
        for (int d = 0; d < 8; ++d) e = fmaf(qreg[r][d], kv[d], e);
        l[r] += __expf(e);
      }
    }
  }
  float invl[4];
#pragma unroll
  for (int r = 0; r < 4; ++r) {
    float t = l[r];
#pragma unroll
    for (int m = 1; m < 64; m <<= 1) t += __shfl_xor(t, m, 64);
    invl[r] = 1.0f / t;
  }

  float acc[4][32];
#pragma unroll
  for (int r = 0; r < 4; ++r)
#pragma unroll
    for (int d = 0; d < 32; ++d) acc[r][d] = 0.f;

  // ---- pass 2: attn store + PV ----
  for (int s = 0; s < 16; ++s) {
    int k0 = s * 256;
    __syncthreads();
    for (int idx = tid; idx < 8 * 256; idx += TPB) {
      int d = idx >> 8, kk = idx & 255;
      k_s[d][kk] = ks[(h * 8 + d) * kHW + k0 + kk];
    }
    for (int idx = tid; idx < 32 * 256; idx += TPB) {
      int d = idx >> 8, kk = idx & 255;
      v_s[kk][d] = vv[(size_t)(h * 32 + d) * kHW + k0 + kk];
    }
    __syncthreads();
#pragma unroll
    for (int sub = 0; sub < 4; ++sub) {
      int kl = sub * 64 + lane;
      float kv[8];
#pragma unroll
      for (int d = 0; d < 8; ++d) kv[d] = k_s[d][kl];
      float p[4];
#pragma unroll
      for (int r = 0; r < 4; ++r) {
        float e = 0.f;
#pragma unroll
        for (int d = 0; d < 8; ++d) e = fmaf(qreg[r][d], kv[d], e);  // identical order to pass1
        p[r] = __expf(e);
      }
#pragma unroll
      for (int r = 0; r < 4; ++r)
        attn_out[((size_t)(h * kHW) + qi0 + r) * kHW + k0 + kl] = p[r] * invl[r];
      float4 v4[8];
#pragma unroll
      for (int j = 0; j < 8; ++j) v4[j] = *(const float4*)&v_s[kl][j * 4];
#pragma unroll
      for (int r = 0; r < 4; ++r) {
#pragma unroll
        for (int j = 0; j < 8; ++j) {
          acc[r][j * 4 + 0] = fmaf(p[r], v4[j].x, acc[r][j * 4 + 0]);
          acc[r][j * 4 + 1] = fmaf(p[r], v4[j].y, acc[r][j * 4 + 1]);
          acc[r][j * 4 + 2] = fmaf(p[r], v4[j].z, acc[r][j * 4 + 2]);
          acc[r][j * 4 + 3] = fmaf(p[r], v4[j].w, acc[r][j * 4 + 3]);
        }
      }
    }
  }
  // cross-lane reduce PV partials, store rr[px][c] (scale by invl)
#pragma unroll
  for (int r = 0; r < 4; ++r) {
    float wval = 0.f;
#pragma unroll
    for (int d = 0; d < 32; ++d) {
      float t = acc[r][d];
#pragma unroll
      for (int m = 1; m < 64; m <<= 1) t += __shfl_xor(t, m, 64);
      if ((lane & 31) == d) wval = t;
    }
    if (lane < 32) rr[(size_t)(qi0 + r) * kC + h * 32 + lane] = wval * invl[r];
  }
}

// ---------------------------------------------------------------- 1x1 conv-o (reads rr [px][c])
__global__ __launch_bounds__(TPB) void k_convo(const float* __restrict__ wsf_c,
                                               const float* __restrict__ bo,
                                               float* __restrict__ wsf) {
  __shared__ float rt[64][65];
  const float* rr = wsf_c + OFF_RR;
  const float* wot = wsf_c + OFF_WOT;
  float* tmp = wsf + OFF_TMP;
  int y = blockIdx.x, cb = blockIdx.y;
  int lane = threadIdx.x & 63, wave = threadIdx.x >> 6;
  int co0 = __builtin_amdgcn_readfirstlane(cb * 64 + (wave << 4));
  int px0 = y * kWid;
  float acc[16];
#pragma unroll
  for (int j = 0; j < 16; ++j) acc[j] = 0.f;
  for (int ch = 0; ch < 4; ++ch) {
    __syncthreads();
    for (int p = wave; p < 64; p += 4) rt[lane][p] = rr[(size_t)(px0 + p) * kC + ch * 64 + lane];
    __syncthreads();
    for (int ci = 0; ci < 64; ++ci) {
      float xv = rt[ci][lane];
      const float* wrow = wot + (size_t)(ch * 64 + ci) * 256 + co0;  // uniform -> s_load
#pragma unroll
      for (int j = 0; j < 16; ++j) acc[j] = fmaf(wrow[j], xv, acc[j]);
    }
  }
#pragma unroll
  for (int j = 0; j < 16; ++j)
    tmp[(size_t)(co0 + j) * kHW + px0 + lane] = acc[j] + bo[co0 + j];
}

// ---------------------------------------------------------------- residual + layernorm + transpose
__global__ __launch_bounds__(TPB) void k_ln(const float* __restrict__ value,
                                            const float* __restrict__ wsf,
                                            const float* __restrict__ g,
                                            const float* __restrict__ b,
                                            float* __restrict__ out0) {
  __shared__ float tv[32][257];
  const float* tmp = wsf + OFF_TMP;
  int tile = blockIdx.x;           // 128 tiles of 32 px
  int tid = threadIdx.x;
  int lane = tid & 63, wave = tid >> 6;
  int base = tile * 32;
  for (int i = tid; i < 32 * 256; i += TPB) {
    int px = i & 31, c = i >> 5;
    tv[px][c] = value[c * kHW + base + px] + tmp[c * kHW + base + px];
  }
  __syncthreads();
  float g0 = g[lane], g1 = g[lane + 64], g2 = g[lane + 128], g3 = g[lane + 192];
  float b0 = b[lane], b1 = b[lane + 64], b2 = b[lane + 128], b3 = b[lane + 192];
  for (int pi = 0; pi < 8; ++pi) {
    int px = wave * 8 + pi;
    float x0 = tv[px][lane], x1 = tv[px][lane + 64], x2 = tv[px][lane + 128], x3 = tv[px][lane + 192];
    float s = x0 + x1 + x2 + x3;
#pragma unroll
    for (int m = 1; m < 64; m <<= 1) s += __shfl_xor(s, m, 64);
    float mu = s * (1.f / 256.f);
    float d0 = x0 - mu, d1 = x1 - mu, d2 = x2 - mu, d3 = x3 - mu;
    float vs = d0 * d0 + d1 * d1 + d2 * d2 + d3 * d3;
#pragma unroll
    for (int m = 1; m < 64; m <<= 1) vs += __shfl_xor(vs, m, 64);
    float rstd = rsqrtf(vs * (1.f / 256.f) + 1e-5f);
    size_t ob = (size_t)(base + px) * 256;
    out0[ob + lane]       = d0 * rstd * g0 + b0;
    out0[ob + lane + 64]  = d1 * rstd * g1 + b1;
    out0[ob + lane + 128] = d2 * rstd * g2 + b2;
    out0[ob + lane + 192] = d3 * rstd * g3 + b3;
  }
}

// ---------------------------------------------------------------- launch
extern "C" void kernel_launch(void* const* d_in, const int* in_sizes, int n_in,
                              void* d_out, int out_size, void* d_ws, size_t ws_size,
                              hipStream_t stream) {
  const float* query = (const float*)d_in[0];
  const float* key   = (const float*)d_in[1];
  const float* value = (const float*)d_in[2];
  const float* qpe   = (const float*)d_in[3];
  const float* kpe   = (const float*)d_in[4];
  const float* wq    = (const float*)d_in[5];
  const float* bq    = (const float*)d_in[6];
  const float* wk    = (const float*)d_in[7];
  const float* bk    = (const float*)d_in[8];
  const float* wv    = (const float*)d_in[9];
  const float* bv    = (const float*)d_in[10];
  const float* wo    = (const float*)d_in[11];
  const float* bo    = (const float*)d_in[12];
  const float* ln_g  = (const float*)d_in[13];
  const float* ln_b  = (const float*)d_in[14];
  float* wsf = (float*)d_ws;
  float* out0 = (float*)d_out;
  float* attn_out = out0 + 1048576;  // tv first (4096*256), then attn (8*4096*4096)

  k_prep<<<576, TPB, 0, stream>>>(wq, wk, wv, wo, wsf);
  k_conv3<<<dim3(64, 4, 2), TPB, 0, stream>>>(query, key, qpe, kpe, wsf);
  k_sumqk<<<1024, TPB, 0, stream>>>(bq, bk, wsf);
  k_convv<<<dim3(64, 4), TPB, 0, stream>>>(value, bv, wsf);
  k_attn<<<dim3(256, 8), TPB, 0, stream>>>(wsf, wsf + OFF_RR, attn_out);
  k_convo<<<dim3(64, 4), TPB, 0, stream>>>(wsf, bo, wsf);
  k_ln<<<128, TPB, 0, stream>>>(value, wsf, ln_g, ln_b, out0);
}